// Round 1
// baseline (598.160 us; speedup 1.0000x reference)
//
#include <hip/hip_runtime.h>
#include <hip/hip_bf16.h>

#define S_LEN 2048
#define HID 4096
#define NH 32
#define NKV 8
#define HD 128

typedef unsigned short u16;
typedef __attribute__((ext_vector_type(4))) float f32x4;
typedef __attribute__((ext_vector_type(8))) short bf16x8;

__device__ __forceinline__ u16 f2bf(float x) {
  union { float f; unsigned u; } c; c.f = x;
  unsigned r = c.u + 0x7FFFu + ((c.u >> 16) & 1u);
  return (u16)(r >> 16);
}

__device__ __forceinline__ void gload16(const void* g, void* l) {
  __builtin_amdgcn_global_load_lds(
      (const __attribute__((address_space(1))) unsigned int*)g,
      (__attribute__((address_space(3))) unsigned int*)l, 16, 0, 0);
}

// ---------------- fp32 -> bf16 convert (float4 / ushort4) ----------------
__global__ void cvt4_kernel(const float* __restrict__ s, u16* __restrict__ d, int n4) {
  int i = blockIdx.x * 256 + threadIdx.x;
  if (i >= n4) return;
  float4 v = ((const float4*)s)[i];
  ushort4 o;
  o.x = f2bf(v.x); o.y = f2bf(v.y); o.z = f2bf(v.z); o.w = f2bf(v.w);
  ((ushort4*)d)[i] = o;
}

// ---------------- rope cos/sin table [S][64] ----------------
__global__ void rope_tab_kernel(float2* __restrict__ tab) {
  int i = blockIdx.x * 256 + threadIdx.x; // S*64
  int t = i >> 6, d = i & 63;
  // inv = THETA^(-d/64) = exp(-d/64 * ln(1e5))
  float inv = expf(-(float)d * (11.512925464970229f / 64.0f));
  float f = (float)t * inv;
  float2 cs; cs.x = cosf(f); cs.y = sinf(f);
  tab[i] = cs;
}

// ---------------- Q rope: qkv fp32 -> Q bf16 [S][NH][128] ----------------
__global__ void rope_q_kernel(const float* __restrict__ qkv, const float2* __restrict__ tab,
                              u16* __restrict__ Q) {
  int i = blockIdx.x * 256 + threadIdx.x; // S*NH*64
  int d = i & 63, h = (i >> 6) & 31, t = i >> 11;
  const float* row = qkv + (size_t)t * 6144 + h * 128;
  float x1 = row[d], x2 = row[d + 64];
  float2 cs = tab[(t << 6) | d];
  u16* orow = Q + (((size_t)t * NH + h) << 7);
  orow[d]      = f2bf(x1 * cs.x - x2 * cs.y);
  orow[d + 64] = f2bf(x1 * cs.y + x2 * cs.x);
}

// ---------------- K conv(2)+rope: -> K bf16 [S][NKV][128] ----------------
__global__ void convrope_k_kernel(const float* __restrict__ qkv, const float* __restrict__ ck,
                                  const float2* __restrict__ tab, u16* __restrict__ K) {
  int i = blockIdx.x * 256 + threadIdx.x; // S*NKV*64
  int d = i & 63, kv = (i >> 6) & 7, t = i >> 9;
  const float* cur = qkv + (size_t)t * 6144 + 4096 + kv * 128;
  float c0 = ck[kv * 2], c1 = ck[kv * 2 + 1];
  float x1 = c1 * cur[d], x2 = c1 * cur[d + 64];
  if (t > 0) { const float* prv = cur - 6144; x1 += c0 * prv[d]; x2 += c0 * prv[d + 64]; }
  float2 cs = tab[(t << 6) | d];
  u16* orow = K + (((size_t)t * NKV + kv) << 7);
  orow[d]      = f2bf(x1 * cs.x - x2 * cs.y);
  orow[d + 64] = f2bf(x1 * cs.y + x2 * cs.x);
}

// ---------------- V conv(2) + transpose: -> VT bf16 [NKV][128][S] ----------------
__global__ __launch_bounds__(256) void convT_v_kernel(const float* __restrict__ qkv,
                                                      const float* __restrict__ cv,
                                                      u16* __restrict__ VT) {
  __shared__ float ld[65][128];
  int tt = blockIdx.x * 64, kv = blockIdx.y;
  float c0 = cv[kv * 2], c1 = cv[kv * 2 + 1];
  for (int idx = threadIdx.x; idx < 65 * 128; idx += 256) {
    int r = idx >> 7, d = idx & 127;
    int t = tt - 1 + r;
    ld[r][d] = (t >= 0) ? qkv[(size_t)t * 6144 + 5120 + kv * 128 + d] : 0.f;
  }
  __syncthreads();
  int d = threadIdx.x >> 1, tc = (threadIdx.x & 1) * 32;
  u16* out = VT + ((size_t)kv * 128 + d) * S_LEN + tt + tc;
#pragma unroll
  for (int j = 0; j < 32; ++j)
    out[j] = f2bf(c0 * ld[tc + j][d] + c1 * ld[tc + j + 1][d]);
}

// ---------------- NT GEMM: C[m,n] = sum_k A[m,k]*B[n,k]  (bf16 in, fp32 out) ----------------
#define BM 128
#define BN 128
#define BK 64

__global__ __launch_bounds__(256, 2) void gemm_nt_kernel(const u16* __restrict__ A,
                                                         const u16* __restrict__ B,
                                                         float* __restrict__ C,
                                                         int M, int N, int K) {
  __shared__ __align__(16) u16 lA[BM * BK];
  __shared__ __align__(16) u16 lB[BN * BK];
  const int tid = threadIdx.x;
  const int wid = tid >> 6, lane = tid & 63;
  const int bm = blockIdx.y * BM, bn = blockIdx.x * BN;
  const int wr = (wid >> 1) * 64, wc = (wid & 1) * 64;
  const int lr = lane & 15, lg = lane >> 4;
  f32x4 acc[4][4] = {};
  const char* Ab = (const char*)A;
  const char* Bb = (const char*)B;
  const int nk = K / BK;
  for (int kt = 0; kt < nk; ++kt) {
    const size_t k0b = (size_t)kt * (BK * 2);
    __syncthreads();
#pragma unroll
    for (int i = 0; i < 4; ++i) {
      int off = (i * 4 + wid) * 1024 + lane * 16;
      int row = off >> 7, inrow = off & 127;
      int sw = inrow ^ ((row & 7) << 4);
      gload16(Ab + (size_t)(bm + row) * (K * 2) + k0b + sw, (char*)lA + (i * 4 + wid) * 1024);
      gload16(Bb + (size_t)(bn + row) * (K * 2) + k0b + sw, (char*)lB + (i * 4 + wid) * 1024);
    }
    __syncthreads();
    bf16x8 af[4][2], bfv[4][2];
#pragma unroll
    for (int m = 0; m < 4; ++m)
#pragma unroll
      for (int ks = 0; ks < 2; ++ks) {
        int row = wr + m * 16 + lr;
        int boff = row * 128 + ((ks * 64 + lg * 16) ^ ((row & 7) << 4));
        af[m][ks] = *(const bf16x8*)((const char*)lA + boff);
      }
#pragma unroll
    for (int n = 0; n < 4; ++n)
#pragma unroll
      for (int ks = 0; ks < 2; ++ks) {
        int row = wc + n * 16 + lr;
        int boff = row * 128 + ((ks * 64 + lg * 16) ^ ((row & 7) << 4));
        bfv[n][ks] = *(const bf16x8*)((const char*)lB + boff);
      }
#pragma unroll
    for (int m = 0; m < 4; ++m)
#pragma unroll
      for (int n = 0; n < 4; ++n)
#pragma unroll
        for (int ks = 0; ks < 2; ++ks)
          acc[m][n] = __builtin_amdgcn_mfma_f32_16x16x32_bf16(af[m][ks], bfv[n][ks], acc[m][n], 0, 0, 0);
  }
#pragma unroll
  for (int m = 0; m < 4; ++m)
#pragma unroll
    for (int n = 0; n < 4; ++n)
#pragma unroll
      for (int r = 0; r < 4; ++r) {
        int row = bm + wr + m * 16 + lg * 4 + r;
        int col = bn + wc + n * 16 + lr;
        C[(size_t)row * N + col] = acc[m][n][r];
      }
}

// ---------------- causal GQA flash attention ----------------
// Q: [S][NH][128] bf16, K: [S][NKV][128] bf16, VT: [NKV][128][S] bf16
// O: [S][NH*128] bf16.  grid = (S/64, NH), 4 waves; wave w owns q-rows w*16..w*16+15.
__global__ __launch_bounds__(256, 2) void attn_kernel(const u16* __restrict__ Q,
                                                      const u16* __restrict__ K,
                                                      const u16* __restrict__ VT,
                                                      u16* __restrict__ O) {
  __shared__ __align__(16) u16 lK[64 * 128];   // [t][d], 256B rows, XOR swizzled
  __shared__ __align__(16) u16 lV[128 * 64];   // [d][t], 128B rows, XOR swizzled
  __shared__ __align__(16) u16 lP[4][16 * 64]; // per-wave P, 128B rows, XOR swizzled
  const int tid = threadIdx.x;
  const int wid = tid >> 6, lane = tid & 63;
  const int lr = lane & 15, lg = lane >> 4;
  const int qt = blockIdx.x, h = blockIdx.y;
  const int kvh = h >> 2;
  const int qrow = qt * 64 + wid * 16 + lr;

  bf16x8 qf[4];
#pragma unroll
  for (int ks = 0; ks < 4; ++ks)
    qf[ks] = *(const bf16x8*)(Q + (((size_t)qrow * NH + h) << 7) + ks * 32 + lg * 8);

  f32x4 o[8] = {};
  float mrow[4], lrow[4];
#pragma unroll
  for (int r = 0; r < 4; ++r) { mrow[r] = -1e30f; lrow[r] = 0.f; }

  const char* Kb = (const char*)K;
  const char* Vb = (const char*)VT;
  const float SC = 0.12752551286084f; // (1/sqrt(128)) * log2(e)

  for (int kt = 0; kt <= qt; ++kt) {
    __syncthreads();
#pragma unroll
    for (int i = 0; i < 4; ++i) {
      int off = (i * 4 + wid) * 1024 + lane * 16;
      int t = off >> 8, inrow = off & 255;
      gload16(Kb + (((size_t)((kt * 64 + t) * NKV + kvh)) << 8) + (inrow ^ ((t & 7) << 4)),
              (char*)lK + (i * 4 + wid) * 1024);
      int d = off >> 7, inr2 = off & 127;
      gload16(Vb + ((size_t)(kvh * 128 + d)) * (S_LEN * 2) + kt * 128 + (inr2 ^ ((d & 7) << 4)),
              (char*)lV + (i * 4 + wid) * 1024);
    }
    __syncthreads();

    // S = Q K^T  (16 x 64 per wave)
    f32x4 sv[4];
#pragma unroll
    for (int n = 0; n < 4; ++n) {
      f32x4 a = {};
#pragma unroll
      for (int ks = 0; ks < 4; ++ks) {
        int trow = n * 16 + lr;
        int boff = trow * 256 + ((ks * 64 + lg * 16) ^ ((trow & 7) << 4));
        bf16x8 kf = *(const bf16x8*)((const char*)lK + boff);
        a = __builtin_amdgcn_mfma_f32_16x16x32_bf16(qf[ks], kf, a, 0, 0, 0);
      }
      sv[n] = a;
    }
    // scale + causal mask (diag tile only)
#pragma unroll
    for (int n = 0; n < 4; ++n)
#pragma unroll
      for (int r = 0; r < 4; ++r)
        sv[n][r] *= SC;
    if (kt == qt) {
#pragma unroll
      for (int n = 0; n < 4; ++n)
#pragma unroll
        for (int r = 0; r < 4; ++r) {
          int col = n * 16 + lr, rw = wid * 16 + lg * 4 + r;
          if (col > rw) sv[n][r] = -1e30f;
        }
    }
    // row max over 64 cols
    float pm[4];
#pragma unroll
    for (int r = 0; r < 4; ++r)
      pm[r] = fmaxf(fmaxf(sv[0][r], sv[1][r]), fmaxf(sv[2][r], sv[3][r]));
#pragma unroll
    for (int r = 0; r < 4; ++r) {
      pm[r] = fmaxf(pm[r], __shfl_xor(pm[r], 1));
      pm[r] = fmaxf(pm[r], __shfl_xor(pm[r], 2));
      pm[r] = fmaxf(pm[r], __shfl_xor(pm[r], 4));
      pm[r] = fmaxf(pm[r], __shfl_xor(pm[r], 8));
    }
    float alpha[4];
#pragma unroll
    for (int r = 0; r < 4; ++r) {
      float mn = fmaxf(mrow[r], pm[r]);
      alpha[r] = exp2f(mrow[r] - mn);
      mrow[r] = mn;
    }
    // P = exp2(sl - m), row sums
    float rs[4] = {0.f, 0.f, 0.f, 0.f};
#pragma unroll
    for (int n = 0; n < 4; ++n)
#pragma unroll
      for (int r = 0; r < 4; ++r) {
        float p = exp2f(sv[n][r] - mrow[r]);
        sv[n][r] = p;
        rs[r] += p;
      }
#pragma unroll
    for (int r = 0; r < 4; ++r) {
      rs[r] += __shfl_xor(rs[r], 1);
      rs[r] += __shfl_xor(rs[r], 2);
      rs[r] += __shfl_xor(rs[r], 4);
      rs[r] += __shfl_xor(rs[r], 8);
      lrow[r] = lrow[r] * alpha[r] + rs[r];
    }
    // rescale O
#pragma unroll
    for (int nt = 0; nt < 8; ++nt)
#pragma unroll
      for (int r = 0; r < 4; ++r)
        o[nt][r] *= alpha[r];
    // P (C-layout) -> wave-private LDS (A-layout source), bf16
    char* pb = (char*)lP[wid];
#pragma unroll
    for (int n = 0; n < 4; ++n)
#pragma unroll
      for (int r = 0; r < 4; ++r) {
        int row = lg * 4 + r, col = n * 16 + lr;
        int boff = (row * 128 + col * 2) ^ ((row & 7) << 4);
        *(u16*)(pb + boff) = f2bf(sv[n][r]);
      }
    // O += P * V
#pragma unroll
    for (int ks = 0; ks < 2; ++ks) {
      int aboff = lr * 128 + ((ks * 64 + lg * 16) ^ ((lr & 7) << 4));
      bf16x8 pf = *(const bf16x8*)((const char*)pb + aboff);
#pragma unroll
      for (int nt = 0; nt < 8; ++nt) {
        int drow = nt * 16 + lr;
        int vboff = drow * 128 + ((ks * 64 + lg * 16) ^ ((drow & 7) << 4));
        bf16x8 vf = *(const bf16x8*)((const char*)lV + vboff);
        o[nt] = __builtin_amdgcn_mfma_f32_16x16x32_bf16(pf, vf, o[nt], 0, 0, 0);
      }
    }
  }
  float rinv[4];
#pragma unroll
  for (int r = 0; r < 4; ++r) rinv[r] = 1.0f / lrow[r];
#pragma unroll
  for (int nt = 0; nt < 8; ++nt)
#pragma unroll
    for (int r = 0; r < 4; ++r) {
      int row = qt * 64 + wid * 16 + lg * 4 + r;
      int col = nt * 16 + lr;
      O[(size_t)row * 4096 + h * 128 + col] = f2bf(o[nt][r] * rinv[r]);
    }
}

extern "C" void kernel_launch(void* const* d_in, const int* in_sizes, int n_in,
                              void* d_out, int out_size, void* d_ws, size_t ws_size,
                              hipStream_t stream) {
  const float* hidden = (const float*)d_in[0];
  const float* wpack  = (const float*)d_in[1];
  const float* wo     = (const float*)d_in[2];
  const float* convk  = (const float*)d_in[3];
  const float* convv  = (const float*)d_in[4];
  float* out = (float*)d_out;

  char* w = (char*)d_ws;
  u16*  hiddenB = (u16*)w;                   // 16,777,216 B (later reused as attn_out)
  u16*  wpackB  = (u16*)(w + 16777216);      // 50,331,648 B (later reused for w_o bf16)
  float* qkv    = (float*)(w + 67108864);    // 50,331,648 B
  u16*  qrope   = (u16*)(w + 117440512);     // 16,777,216 B
  u16*  krope   = (u16*)(w + 134217728);     //  4,194,304 B
  u16*  vT      = (u16*)(w + 138412032);     //  4,194,304 B
  float2* tab   = (float2*)(w + 142606336);  //  1,048,576 B

  cvt4_kernel<<<8192, 256, 0, stream>>>(hidden, hiddenB, 2097152);
  cvt4_kernel<<<24576, 256, 0, stream>>>(wpack, wpackB, 6291456);
  rope_tab_kernel<<<512, 256, 0, stream>>>(tab);
  gemm_nt_kernel<<<dim3(48, 16), 256, 0, stream>>>(hiddenB, wpackB, qkv, 2048, 6144, 4096);
  cvt4_kernel<<<16384, 256, 0, stream>>>(wo, wpackB, 4194304); // reuse wpackB for w_o bf16
  rope_q_kernel<<<16384, 256, 0, stream>>>(qkv, tab, qrope);
  convrope_k_kernel<<<4096, 256, 0, stream>>>(qkv, convk, tab, krope);
  convT_v_kernel<<<dim3(32, 8), 256, 0, stream>>>(qkv, convv, vT);
  attn_kernel<<<dim3(32, 32), 256, 0, stream>>>(qrope, krope, vT, hiddenB); // attn_out -> hiddenB
  gemm_nt_kernel<<<dim3(32, 16), 256, 0, stream>>>(hiddenB, wpackB, out, 2048, 4096, 4096);
}

// Round 2
// 530.177 us; speedup vs baseline: 1.1282x; 1.1282x over previous
//
#include <hip/hip_runtime.h>
#include <hip/hip_bf16.h>

#define S_LEN 2048
#define HID 4096
#define NH 32
#define NKV 8
#define HD 128

typedef unsigned short u16;
typedef __attribute__((ext_vector_type(4))) float f32x4;
typedef __attribute__((ext_vector_type(8))) short bf16x8;

__device__ __forceinline__ u16 f2bf(float x) {
  union { float f; unsigned u; } c; c.f = x;
  unsigned r = c.u + 0x7FFFu + ((c.u >> 16) & 1u);
  return (u16)(r >> 16);
}

__device__ __forceinline__ void gload16(const void* g, void* l) {
  __builtin_amdgcn_global_load_lds(
      (const __attribute__((address_space(1))) unsigned int*)g,
      (__attribute__((address_space(3))) unsigned int*)l, 16, 0, 0);
}

// ---------------- fp32 -> bf16 convert (float4 / ushort4) ----------------
__global__ void cvt4_kernel(const float* __restrict__ s, u16* __restrict__ d, int n4) {
  int i = blockIdx.x * 256 + threadIdx.x;
  if (i >= n4) return;
  float4 v = ((const float4*)s)[i];
  ushort4 o;
  o.x = f2bf(v.x); o.y = f2bf(v.y); o.z = f2bf(v.z); o.w = f2bf(v.w);
  ((ushort4*)d)[i] = o;
}

// ---------------- rope cos/sin table [S][64] ----------------
__global__ void rope_tab_kernel(float2* __restrict__ tab) {
  int i = blockIdx.x * 256 + threadIdx.x; // S*64
  int t = i >> 6, d = i & 63;
  float inv = expf(-(float)d * (11.512925464970229f / 64.0f));
  float f = (float)t * inv;
  float2 cs; cs.x = cosf(f); cs.y = sinf(f);
  tab[i] = cs;
}

// ---------------- Q rope (pre-scaled by log2e/sqrt(D)): qkv fp32 -> Q bf16 [S][NH][128] ----------------
__global__ void rope_q_kernel(const float* __restrict__ qkv, const float2* __restrict__ tab,
                              u16* __restrict__ Q) {
  int i = blockIdx.x * 256 + threadIdx.x; // S*NH*64
  int d = i & 63, h = (i >> 6) & 31, t = i >> 11;
  const float* row = qkv + (size_t)t * 6144 + h * 128;
  float x1 = row[d], x2 = row[d + 64];
  float2 cs = tab[(t << 6) | d];
  const float SC = 0.12752551286084f; // (1/sqrt(128)) * log2(e)
  u16* orow = Q + (((size_t)t * NH + h) << 7);
  orow[d]      = f2bf((x1 * cs.x - x2 * cs.y) * SC);
  orow[d + 64] = f2bf((x1 * cs.y + x2 * cs.x) * SC);
}

// ---------------- K conv(2)+rope: -> K bf16 [S][NKV][128] ----------------
__global__ void convrope_k_kernel(const float* __restrict__ qkv, const float* __restrict__ ck,
                                  const float2* __restrict__ tab, u16* __restrict__ K) {
  int i = blockIdx.x * 256 + threadIdx.x; // S*NKV*64
  int d = i & 63, kv = (i >> 6) & 7, t = i >> 9;
  const float* cur = qkv + (size_t)t * 6144 + 4096 + kv * 128;
  float c0 = ck[kv * 2], c1 = ck[kv * 2 + 1];
  float x1 = c1 * cur[d], x2 = c1 * cur[d + 64];
  if (t > 0) { const float* prv = cur - 6144; x1 += c0 * prv[d]; x2 += c0 * prv[d + 64]; }
  float2 cs = tab[(t << 6) | d];
  u16* orow = K + (((size_t)t * NKV + kv) << 7);
  orow[d]      = f2bf(x1 * cs.x - x2 * cs.y);
  orow[d + 64] = f2bf(x1 * cs.y + x2 * cs.x);
}

// ---------------- V conv(2) + transpose: -> VT bf16 [NKV][128][S] ----------------
__global__ __launch_bounds__(256) void convT_v_kernel(const float* __restrict__ qkv,
                                                      const float* __restrict__ cv,
                                                      u16* __restrict__ VT) {
  __shared__ float ld[65][128];
  int tt = blockIdx.x * 64, kv = blockIdx.y;
  float c0 = cv[kv * 2], c1 = cv[kv * 2 + 1];
  for (int idx = threadIdx.x; idx < 65 * 128; idx += 256) {
    int r = idx >> 7, d = idx & 127;
    int t = tt - 1 + r;
    ld[r][d] = (t >= 0) ? qkv[(size_t)t * 6144 + 5120 + kv * 128 + d] : 0.f;
  }
  __syncthreads();
  int d = threadIdx.x >> 1, tc = (threadIdx.x & 1) * 32;
  u16* out = VT + ((size_t)kv * 128 + d) * S_LEN + tt + tc;
#pragma unroll
  for (int j = 0; j < 32; ++j)
    out[j] = f2bf(c0 * ld[tc + j][d] + c1 * ld[tc + j + 1][d]);
}

// ---------------- NT GEMM: C[m,n] = sum_k A[m,k]*B[n,k]  (bf16 in, fp32 out) ----------------
#define BM 128
#define BN 128
#define BK 64

__global__ __launch_bounds__(256, 2) void gemm_nt_kernel(const u16* __restrict__ A,
                                                         const u16* __restrict__ B,
                                                         float* __restrict__ C,
                                                         int M, int N, int K) {
  __shared__ __align__(16) u16 lA[BM * BK];
  __shared__ __align__(16) u16 lB[BN * BK];
  const int tid = threadIdx.x;
  const int wid = tid >> 6, lane = tid & 63;
  const int bm = blockIdx.y * BM, bn = blockIdx.x * BN;
  const int wr = (wid >> 1) * 64, wc = (wid & 1) * 64;
  const int lr = lane & 15, lg = lane >> 4;
  f32x4 acc[4][4] = {};
  const char* Ab = (const char*)A;
  const char* Bb = (const char*)B;
  const int nk = K / BK;
  for (int kt = 0; kt < nk; ++kt) {
    const size_t k0b = (size_t)kt * (BK * 2);
    __syncthreads();
#pragma unroll
    for (int i = 0; i < 4; ++i) {
      int off = (i * 4 + wid) * 1024 + lane * 16;
      int row = off >> 7, inrow = off & 127;
      int sw = inrow ^ ((row & 7) << 4);
      gload16(Ab + (size_t)(bm + row) * (K * 2) + k0b + sw, (char*)lA + (i * 4 + wid) * 1024);
      gload16(Bb + (size_t)(bn + row) * (K * 2) + k0b + sw, (char*)lB + (i * 4 + wid) * 1024);
    }
    __syncthreads();
    bf16x8 af[4][2], bfv[4][2];
#pragma unroll
    for (int m = 0; m < 4; ++m)
#pragma unroll
      for (int ks = 0; ks < 2; ++ks) {
        int row = wr + m * 16 + lr;
        int boff = row * 128 + ((ks * 64 + lg * 16) ^ ((row & 7) << 4));
        af[m][ks] = *(const bf16x8*)((const char*)lA + boff);
      }
#pragma unroll
    for (int n = 0; n < 4; ++n)
#pragma unroll
      for (int ks = 0; ks < 2; ++ks) {
        int row = wc + n * 16 + lr;
        int boff = row * 128 + ((ks * 64 + lg * 16) ^ ((row & 7) << 4));
        bfv[n][ks] = *(const bf16x8*)((const char*)lB + boff);
      }
#pragma unroll
    for (int m = 0; m < 4; ++m)
#pragma unroll
      for (int n = 0; n < 4; ++n)
#pragma unroll
        for (int ks = 0; ks < 2; ++ks)
          acc[m][n] = __builtin_amdgcn_mfma_f32_16x16x32_bf16(af[m][ks], bfv[n][ks], acc[m][n], 0, 0, 0);
  }
#pragma unroll
  for (int m = 0; m < 4; ++m)
#pragma unroll
    for (int n = 0; n < 4; ++n)
#pragma unroll
      for (int r = 0; r < 4; ++r) {
        int row = bm + wr + m * 16 + lg * 4 + r;
        int col = bn + wc + n * 16 + lr;
        C[(size_t)row * N + col] = acc[m][n][r];
      }
}

// ---------------- causal GQA flash attention (paired q-tiles, double-buffered) ----------------
// Q: [S][NH][128] bf16 (pre-scaled), K: [S][NKV][128] bf16, VT: [NKV][128][S] bf16
// O: [S][NH*128] bf16. grid = (16, NH); block handles q-tiles q0 and 31-q0 (33 tile-steps const).
__global__ __launch_bounds__(256, 2) void attn_kernel(const u16* __restrict__ Q,
                                                      const u16* __restrict__ K,
                                                      const u16* __restrict__ VT,
                                                      u16* __restrict__ O) {
  __shared__ __align__(16) u16 lK[2][64 * 128];   // [t][d], 256B rows, XOR swizzled
  __shared__ __align__(16) u16 lV[2][128 * 64];   // [d][t], 128B rows, XOR swizzled
  __shared__ __align__(16) u16 lP[4][16 * 64];    // per-wave P, 128B rows, XOR swizzled
  const int tid = threadIdx.x;
  const int wid = tid >> 6, lane = tid & 63;
  const int lr = lane & 15, lg = lane >> 4;
  const int q0 = blockIdx.x, h = blockIdx.y;
  const int kvh = h >> 2;
  const int qtA = q0, qtB = 31 - q0;

  bf16x8 qfA[4], qfB[4];
  {
    const int rA = qtA * 64 + wid * 16 + lr;
    const int rB = qtB * 64 + wid * 16 + lr;
#pragma unroll
    for (int ks = 0; ks < 4; ++ks) {
      qfA[ks] = *(const bf16x8*)(Q + (((size_t)rA * NH + h) << 7) + ks * 32 + lg * 8);
      qfB[ks] = *(const bf16x8*)(Q + (((size_t)rB * NH + h) << 7) + ks * 32 + lg * 8);
    }
  }

  f32x4 oA[8] = {}, oB[8] = {};
  float mA[4], lsA[4], mB[4], lsB[4];
#pragma unroll
  for (int r = 0; r < 4; ++r) { mA[r] = mB[r] = -1e30f; lsA[r] = lsB[r] = 0.f; }

  const char* Kb = (const char*)K;
  const char* Vb = (const char*)VT;
  char* pb = (char*)lP[wid];

  auto stage = [&](int buf, int kt) {
    char* dK = (char*)lK[buf];
    char* dV = (char*)lV[buf];
#pragma unroll
    for (int i = 0; i < 4; ++i) {
      int off = (i * 4 + wid) * 1024 + lane * 16;
      int t = off >> 8, inrow = off & 255;
      gload16(Kb + (((size_t)((kt * 64 + t) * NKV + kvh)) << 8) + (inrow ^ ((t & 7) << 4)),
              dK + (i * 4 + wid) * 1024);
      int d = off >> 7, inr2 = off & 127;
      gload16(Vb + ((size_t)(kvh * 128 + d)) * (S_LEN * 2) + kt * 128 + (inr2 ^ ((d & 7) << 4)),
              dV + (i * 4 + wid) * 1024);
    }
  };

  auto step = [&](const bf16x8* qf, f32x4* o, float* mrow, float* lrow, int buf, bool diag) {
    const char* kb = (const char*)lK[buf];
    const char* vb = (const char*)lV[buf];
    // S = Q K^T (16 x 64 per wave); Q pre-scaled so sv is in log2 domain
    f32x4 sv[4];
#pragma unroll
    for (int n = 0; n < 4; ++n) {
      f32x4 a = {};
#pragma unroll
      for (int ks = 0; ks < 4; ++ks) {
        int trow = n * 16 + lr;
        int boff = trow * 256 + ((ks * 64 + lg * 16) ^ ((trow & 7) << 4));
        bf16x8 kf = *(const bf16x8*)(kb + boff);
        a = __builtin_amdgcn_mfma_f32_16x16x32_bf16(qf[ks], kf, a, 0, 0, 0);
      }
      sv[n] = a;
    }
    if (diag) {
#pragma unroll
      for (int n = 0; n < 4; ++n)
#pragma unroll
        for (int r = 0; r < 4; ++r) {
          int col = n * 16 + lr, rw = wid * 16 + lg * 4 + r;
          if (col > rw) sv[n][r] = -1e30f;
        }
    }
    // row max over 64 cols
    float pm[4];
#pragma unroll
    for (int r = 0; r < 4; ++r)
      pm[r] = fmaxf(fmaxf(sv[0][r], sv[1][r]), fmaxf(sv[2][r], sv[3][r]));
#pragma unroll
    for (int r = 0; r < 4; ++r) {
      pm[r] = fmaxf(pm[r], __shfl_xor(pm[r], 1));
      pm[r] = fmaxf(pm[r], __shfl_xor(pm[r], 2));
      pm[r] = fmaxf(pm[r], __shfl_xor(pm[r], 4));
      pm[r] = fmaxf(pm[r], __shfl_xor(pm[r], 8));
    }
    // defer-max: only rescale when some row grew past THR=8 (log2 units)
    bool need = (pm[0] > mrow[0] + 8.f) | (pm[1] > mrow[1] + 8.f) |
                (pm[2] > mrow[2] + 8.f) | (pm[3] > mrow[3] + 8.f);
    if (__any(need)) {
#pragma unroll
      for (int r = 0; r < 4; ++r) {
        float mn = fmaxf(mrow[r], pm[r]);
        float al = exp2f(mrow[r] - mn);
        mrow[r] = mn;
        lrow[r] *= al;
#pragma unroll
        for (int nt = 0; nt < 8; ++nt) o[nt][r] *= al;
      }
    }
    // P = exp2(sv - m), write to wave-private LDS (A-layout), accumulate row sums
    float rs[4] = {0.f, 0.f, 0.f, 0.f};
#pragma unroll
    for (int n = 0; n < 4; ++n)
#pragma unroll
      for (int r = 0; r < 4; ++r) {
        float p = exp2f(sv[n][r] - mrow[r]);
        rs[r] += p;
        int row = lg * 4 + r, col = n * 16 + lr;
        int boff = (row * 128 + col * 2) ^ ((row & 7) << 4);
        *(u16*)(pb + boff) = f2bf(p);
      }
#pragma unroll
    for (int r = 0; r < 4; ++r) {
      rs[r] += __shfl_xor(rs[r], 1);
      rs[r] += __shfl_xor(rs[r], 2);
      rs[r] += __shfl_xor(rs[r], 4);
      rs[r] += __shfl_xor(rs[r], 8);
      lrow[r] += rs[r];
    }
    // O += P * V
#pragma unroll
    for (int ks = 0; ks < 2; ++ks) {
      int aboff = lr * 128 + ((ks * 64 + lg * 16) ^ ((lr & 7) << 4));
      bf16x8 pf = *(const bf16x8*)(pb + aboff);
#pragma unroll
      for (int nt = 0; nt < 8; ++nt) {
        int drow = nt * 16 + lr;
        int vboff = drow * 128 + ((ks * 64 + lg * 16) ^ ((drow & 7) << 4));
        bf16x8 vf = *(const bf16x8*)(vb + vboff);
        o[nt] = __builtin_amdgcn_mfma_f32_16x16x32_bf16(pf, vf, o[nt], 0, 0, 0);
      }
    }
  };

  stage(0, 0);
  __syncthreads();
  for (int kt = 0; kt <= qtB; ++kt) {
    int cur = kt & 1;
    if (kt < qtB) stage(cur ^ 1, kt + 1);
    if (kt <= qtA) step(qfA, oA, mA, lsA, cur, kt == qtA);
    step(qfB, oB, mB, lsB, cur, kt == qtB);
    __syncthreads();
  }

#pragma unroll
  for (int r = 0; r < 4; ++r) { lsA[r] = 1.0f / lsA[r]; lsB[r] = 1.0f / lsB[r]; }
#pragma unroll
  for (int nt = 0; nt < 8; ++nt)
#pragma unroll
    for (int r = 0; r < 4; ++r) {
      int rowA = qtA * 64 + wid * 16 + lg * 4 + r;
      int rowB = qtB * 64 + wid * 16 + lg * 4 + r;
      int col = nt * 16 + lr;
      O[(size_t)rowA * 4096 + h * 128 + col] = f2bf(oA[nt][r] * lsA[r]);
      O[(size_t)rowB * 4096 + h * 128 + col] = f2bf(oB[nt][r] * lsB[r]);
    }
}

extern "C" void kernel_launch(void* const* d_in, const int* in_sizes, int n_in,
                              void* d_out, int out_size, void* d_ws, size_t ws_size,
                              hipStream_t stream) {
  const float* hidden = (const float*)d_in[0];
  const float* wpack  = (const float*)d_in[1];
  const float* wo     = (const float*)d_in[2];
  const float* convk  = (const float*)d_in[3];
  const float* convv  = (const float*)d_in[4];
  float* out = (float*)d_out;

  char* w = (char*)d_ws;
  u16*  hiddenB = (u16*)w;                   // 16,777,216 B (later reused as attn_out)
  u16*  wpackB  = (u16*)(w + 16777216);      // 50,331,648 B (later reused for w_o bf16)
  float* qkv    = (float*)(w + 67108864);    // 50,331,648 B
  u16*  qrope   = (u16*)(w + 117440512);     // 16,777,216 B
  u16*  krope   = (u16*)(w + 134217728);     //  4,194,304 B
  u16*  vT      = (u16*)(w + 138412032);     //  4,194,304 B
  float2* tab   = (float2*)(w + 142606336);  //  1,048,576 B

  cvt4_kernel<<<8192, 256, 0, stream>>>(hidden, hiddenB, 2097152);
  cvt4_kernel<<<24576, 256, 0, stream>>>(wpack, wpackB, 6291456);
  rope_tab_kernel<<<512, 256, 0, stream>>>(tab);
  gemm_nt_kernel<<<dim3(48, 16), 256, 0, stream>>>(hiddenB, wpackB, qkv, 2048, 6144, 4096);
  cvt4_kernel<<<16384, 256, 0, stream>>>(wo, wpackB, 4194304); // reuse wpackB for w_o bf16
  rope_q_kernel<<<16384, 256, 0, stream>>>(qkv, tab, qrope);
  convrope_k_kernel<<<4096, 256, 0, stream>>>(qkv, convk, tab, krope);
  convT_v_kernel<<<dim3(32, 8), 256, 0, stream>>>(qkv, convv, vT);
  attn_kernel<<<dim3(16, 32), 256, 0, stream>>>(qrope, krope, vT, hiddenB); // attn_out -> hiddenB
  gemm_nt_kernel<<<dim3(32, 16), 256, 0, stream>>>(hiddenB, wpackB, out, 2048, 4096, 4096);
}